// Round 4
// baseline (141.440 us; speedup 1.0000x reference)
//
#include <hip/hip_runtime.h>

#define H 1024
#define W 1024
#define NC 12   // channels
#define ND 8    // depth
#define HG 16
#define WG 16
#define CELL (ND * NC)      // 96 floats per x-cell
#define SLAB (WG * CELL)    // 1536 floats = 6 KB per wave
#define HWSZ (H * W)

typedef float f32x4 __attribute__((ext_vector_type(4)));

// Block = 4 waves, blockIdx.x = y-pair, blockIdx.y = n.  Wave w handles row
// y0+(w>>1), x-half (w&1)*512, with a WAVE-PRIVATE 6 KB LDS slab -> no
// __syncthreads anywhere (no inter-wave convoy).  Lane l owns px 4l of each
// 256-px chunk: every guide load / output store is 64 lanes x 16 B fully
// contiguous (1 KB/instr, same pattern as the 6.4 TB/s fill kernel).
// Staging enumeration x=(4k+ln>>4)&15, m=(ln&15)+16K gives 16-distinct-bank
// LDS writes (4-way, ~free) and whole-64B-line grid reads (no overfetch).
// Compute reads in [x][z*12+c] layout: the 8 z-values tile all 32 banks.
__global__ __launch_bounds__(256, 4) void slice_kernel(
    const float* __restrict__ grid,
    const float* __restrict__ guide,
    float* __restrict__ out)
{
    const int tid = threadIdx.x;
    const int wv  = tid >> 6;          // wave 0..3
    const int ln  = tid & 63;          // lane
    const int n   = blockIdx.y;
    const int y   = blockIdx.x * 2 + (wv >> 1);
    const int xw  = (wv & 1) * 512;    // wave's x-base within the row

    __shared__ __align__(16) float sg[4][SLAB];
    float* S = sg[wv];

    // ---- guide loads first (HBM latency overlaps staging below)
    const float* gd = guide + ((size_t)n * H + y) * W + xw;
    const float4 ga = *(const float4*)&gd[ln * 4];
    const float4 gb = *(const float4*)&gd[256 + ln * 4];

    // ---- y-interp factors (wave-uniform)
    float iy = fminf((float)y * (15.0f / 1023.0f), 15.0f);
    const int   iy0 = (int)iy;
    const int   iy1 = min(iy0 + 1, HG - 1);
    const float wy  = iy - (float)iy0;

    // ---- stage wave-private y-interpolated slab (1536 floats, 24/lane)
    const float* gslab = grid + (size_t)n * (NC * ND * HG * WG);
    const int lx = ln >> 4;            // 0..3
    const int lm = ln & 15;            // 0..15
    #pragma unroll
    for (int K = 0; K < 6; ++K) {
        const int m = lm + (K << 4);              // zc index 0..95 (= z*12+c)
        const int z = (m * 171) >> 11;            // m / 12  (exact for m<96)
        const int c = m - z * 12;
        const float* gp = gslab + (size_t)((c * ND + z) * HG) * WG;
        const float* g0 = gp + iy0 * WG;
        const float* g1 = gp + iy1 * WG;
        #pragma unroll
        for (int j = 0; j < 4; ++j) {
            const int k = (K << 2) + j;
            const int x = ((k << 2) + lx) & 15;
            const float r0 = g0[x];
            const float r1 = g1[x];
            S[x * CELL + m] = r0 + (r1 - r0) * wy;
        }
    }
    // no barrier: slab is wave-private (compiler inserts the lgkmcnt wait)

    float* obase = out + ((size_t)n * NC * H + y) * W;   // + c*HW + x

    #pragma unroll
    for (int ch = 0; ch < 2; ++ch) {
        const float4 g  = ch ? gb : ga;
        const int    xb = xw + ch * 256 + (ln << 2);     // 4 consecutive px
        const float gz4[4] = { g.x, g.y, g.z, g.w };

        // per-pixel corner cell addresses + bilinear (x,z) dot-weights
        int   A00[4], A01[4], A10[4], A11[4];
        float w00[4], w01[4], w10[4], w11[4];
        #pragma unroll
        for (int p = 0; p < 4; ++p) {
            const int x = xb + p;
            float ix = fminf((float)x * (15.0f / 1023.0f), 15.0f);
            const int   ix0 = (int)ix;
            const int   ix1 = min(ix0 + 1, WG - 1);
            const float wx  = ix - (float)ix0;

            float iz = fminf(fmaxf(gz4[p] * 7.0f, 0.0f), 7.0f);
            const int   iz0 = (int)iz;
            const int   iz1 = min(iz0 + 1, ND - 1);
            const float wz  = iz - (float)iz0;

            A00[p] = ix0 * CELL + iz0 * NC;
            A01[p] = ix0 * CELL + iz1 * NC;
            A10[p] = ix1 * CELL + iz0 * NC;
            A11[p] = ix1 * CELL + iz1 * NC;

            const float ux = 1.0f - wx;
            const float uz = 1.0f - wz;
            w00[p] = ux * uz;  w01[p] = ux * wz;
            w10[p] = wx * uz;  w11[p] = wx * wz;
        }

        #pragma unroll
        for (int cc = 0; cc < NC; cc += 4) {
            float4 q[4];
            #pragma unroll
            for (int p = 0; p < 4; ++p) {
                const float4 a0 = *(const float4*)&S[A00[p] + cc];
                const float4 a1 = *(const float4*)&S[A01[p] + cc];
                const float4 b0 = *(const float4*)&S[A10[p] + cc];
                const float4 b1 = *(const float4*)&S[A11[p] + cc];
                const float k00 = w00[p], k01 = w01[p], k10 = w10[p], k11 = w11[p];
                q[p].x = a0.x * k00 + a1.x * k01 + b0.x * k10 + b1.x * k11;
                q[p].y = a0.y * k00 + a1.y * k01 + b0.y * k10 + b1.y * k11;
                q[p].z = a0.z * k00 + a1.z * k01 + b0.z * k10 + b1.z * k11;
                q[p].w = a0.w * k00 + a1.w * k01 + b0.w * k10 + b1.w * k11;
            }
            f32x4 v;
            v = (f32x4){ q[0].x, q[1].x, q[2].x, q[3].x };
            __builtin_nontemporal_store(v, (f32x4*)&obase[(size_t)(cc + 0) * HWSZ + xb]);
            v = (f32x4){ q[0].y, q[1].y, q[2].y, q[3].y };
            __builtin_nontemporal_store(v, (f32x4*)&obase[(size_t)(cc + 1) * HWSZ + xb]);
            v = (f32x4){ q[0].z, q[1].z, q[2].z, q[3].z };
            __builtin_nontemporal_store(v, (f32x4*)&obase[(size_t)(cc + 2) * HWSZ + xb]);
            v = (f32x4){ q[0].w, q[1].w, q[2].w, q[3].w };
            __builtin_nontemporal_store(v, (f32x4*)&obase[(size_t)(cc + 3) * HWSZ + xb]);
        }
    }
}

extern "C" void kernel_launch(void* const* d_in, const int* in_sizes, int n_in,
                              void* d_out, int out_size, void* d_ws, size_t ws_size,
                              hipStream_t stream) {
    const float* grid  = (const float*)d_in[0];
    const float* guide = (const float*)d_in[1];
    float* out = (float*)d_out;

    dim3 grd(H / 2, 2);   // (y-pair, n) = 512 x 2 = 1024 blocks (4/CU exact)
    dim3 blk(256);
    slice_kernel<<<grd, blk, 0, stream>>>(grid, guide, out);
}